// Round 6
// baseline (732.592 us; speedup 1.0000x reference)
//
#include <hip/hip_runtime.h>
#include <math.h>

#define S_ 448
#define B_ 64
#define F_ 8
#define D_ 256
#define H_ 8
#define DK_ 32
#define L_ 4
#define PRED_ 96
#define NT_ (S_ * B_)          // 28672 tokens
#define PANEL_ (S_ * DK_)      // 14336 elems per (b,h) panel

typedef unsigned short bf16_t;
using bf16x8 = __attribute__((ext_vector_type(8))) short;   // 8 bf16 = 4 VGPR
using f32x4  = __attribute__((ext_vector_type(4))) float;   // MFMA acc

__device__ __forceinline__ float b2f(bf16_t b) {
  return __uint_as_float(((unsigned)b) << 16);
}
__device__ __forceinline__ bf16_t f2b(float f) {
  unsigned u = __float_as_uint(f);
  u += 0x7fffu + ((u >> 16) & 1u);     // round-to-nearest-even
  return (bf16_t)(u >> 16);
}

// ---------------------------------------------------------------- embed
__global__ __launch_bounds__(256) void embed_kernel(
    const float* __restrict__ src, const float* __restrict__ w_in,
    const float* __restrict__ b_in, bf16_t* __restrict__ x) {
  int n = blockIdx.x;          // token = s*B + b
  int d = threadIdx.x;         // 0..255
  const float* srow = src + (size_t)n * F_;
  float acc = b_in[d];
#pragma unroll
  for (int f = 0; f < F_; ++f) acc += srow[f] * w_in[f * D_ + d];
  int s = n / B_;
  int i2 = d & ~1;             // 2*i
  float freq = __expf(-9.210340371976184f * (float)i2 / (float)D_);
  float ang = (float)s * freq;
  float pe = (d & 1) ? cosf(ang) : sinf(ang);
  x[(size_t)n * D_ + d] = f2b(acc + pe);
}

// ------------------------------------------- weight transpose+convert prep
// Wt[l][n][k] (bf16) = W[l][k][n] (f32);  grid (8,8,L), block (32,8)
__global__ __launch_bounds__(256) void transpose_w_kernel(
    const float* __restrict__ W, bf16_t* __restrict__ Wt) {
  __shared__ float t[32][33];
  int l = blockIdx.z;
  int k0 = blockIdx.x * 32, n0 = blockIdx.y * 32;
  int x = threadIdx.x, y = threadIdx.y;
  const float* src = W + ((size_t)l * 256 + k0) * 256 + n0;
#pragma unroll
  for (int i = y; i < 32; i += 8) t[i][x] = src[(size_t)i * 256 + x];
  __syncthreads();
  bf16_t* dst = Wt + ((size_t)l * 256 + n0) * 256 + k0;
#pragma unroll
  for (int i = y; i < 32; i += 8) dst[(size_t)i * 256 + x] = f2b(t[x][i]);
}

// ------------------------------------------------- MFMA GEMM 128x128, BK=32
// ALAY: 0 = token-major [n][256], 1 = head-panel [(b*8+h)][s][dk]
// OLAY: same meaning for output.
template <int ALAY, int OLAY, int RELU>
__device__ __forceinline__ void gemm_body(
    const bf16_t* __restrict__ A, const bf16_t* __restrict__ Wt,
    const float* __restrict__ bias, bf16_t* __restrict__ Y, int m0, int n0) {
  __shared__ bf16_t As[2][128][32];
  __shared__ bf16_t Bs[2][128][32];
  int tid = threadIdx.x, lane = tid & 63, wv = tid >> 6;
  int wr = wv >> 1, wc = wv & 1;           // wave 64x64 sub-tile
  int jg = lane >> 4, fr = lane & 15;
  int s_row = wv * 32 + (lane >> 2);       // + i*16
  int s_p = lane & 3;

  uint4 rA[2], rB[2];

  auto stage_load = [&](int kt) {
    int k0 = kt * 32;
#pragma unroll
    for (int i = 0; i < 2; ++i) {
      int row = s_row + i * 16;
      int ls = s_p ^ ((row >> 1) & 3);
      const bf16_t* ap;
      if (ALAY == 0) {
        ap = A + (size_t)(m0 + row) * 256 + k0 + ls * 8;
      } else {
        int n = m0 + row;                  // token: s = n>>6, b = n&63
        int k = k0 + ls * 8;               // d: h = k>>5, dk = k&31
        ap = A + ((size_t)(((n & 63) << 3) | (k >> 5)) * S_ + (n >> 6)) * DK_ +
             (k & 31);
      }
      rA[i] = *(const uint4*)ap;
      rB[i] = *(const uint4*)(Wt + (size_t)(n0 + row) * 256 + k0 + ls * 8);
    }
  };
  auto stage_write = [&](int buf) {
#pragma unroll
    for (int i = 0; i < 2; ++i) {
      int row = s_row + i * 16;
      *(uint4*)(&As[buf][row][s_p * 8]) = rA[i];
      *(uint4*)(&Bs[buf][row][s_p * 8]) = rB[i];
    }
  };

  f32x4 zero = {0.f, 0.f, 0.f, 0.f};
  f32x4 acc[4][4];
#pragma unroll
  for (int i = 0; i < 4; ++i)
#pragma unroll
    for (int j = 0; j < 4; ++j) acc[i][j] = zero;

  stage_load(0);
  stage_write(0);
  __syncthreads();

  for (int kt = 0; kt < 8; ++kt) {
    int buf = kt & 1;
    if (kt < 7) stage_load(kt + 1);
    bf16x8 af[4], bfr[4];
#pragma unroll
    for (int mi = 0; mi < 4; ++mi) {
      int row = wr * 64 + mi * 16 + fr;
      af[mi] = *(const bf16x8*)((const char*)&As[buf][0][0] + row * 64 +
                                ((jg ^ ((row >> 1) & 3)) << 4));
      int rn = wc * 64 + mi * 16 + fr;
      bfr[mi] = *(const bf16x8*)((const char*)&Bs[buf][0][0] + rn * 64 +
                                 ((jg ^ ((rn >> 1) & 3)) << 4));
    }
#pragma unroll
    for (int mi = 0; mi < 4; ++mi)
#pragma unroll
      for (int ni = 0; ni < 4; ++ni)
        acc[mi][ni] = __builtin_amdgcn_mfma_f32_16x16x32_bf16(
            af[mi], bfr[ni], acc[mi][ni], 0, 0, 0);
    if (kt < 7) {
      stage_write((kt + 1) & 1);
      __syncthreads();
    }
  }

  // ---- epilogue: per-wave LDS transpose -> 16B/lane full-line stores
  __syncthreads();            // everyone done reading As/Bs
  char* ep0 = (char*)&As[0][0][0] + wv * 2048;   // 16 rows x 128 B per wave
  float bcol[4];
#pragma unroll
  for (int ni = 0; ni < 4; ++ni) bcol[ni] = bias[n0 + wc * 64 + ni * 16 + fr];
#pragma unroll
  for (int mi = 0; mi < 4; ++mi) {
    char* ep = ep0 + (mi & 1) * 8192;            // WAR double-buffer
#pragma unroll
    for (int ni = 0; ni < 4; ++ni)
#pragma unroll
      for (int r = 0; r < 4; ++r) {
        float v = acc[mi][ni][r] + bcol[ni];
        if (RELU) v = fmaxf(v, 0.f);
        int row = jg * 4 + r;
        int cb = (ni * 16 + fr) * 2;
        *(bf16_t*)(ep + row * 128 + (cb ^ (jg << 4))) = f2b(v);
      }
    int r0 = lane >> 3, cch = lane & 7;
#pragma unroll
    for (int hf = 0; hf < 2; ++hf) {
      int row16 = r0 + hf * 8;
      uint4 v = *(uint4*)(ep + row16 * 128 +
                          ((cch << 4) ^ (((row16 >> 2) & 3) << 4)));
      int n = m0 + wr * 64 + mi * 16 + row16;
      if (OLAY == 0) {
        *(uint4*)((char*)(Y + (size_t)n * 256 + n0 + wc * 64) + cch * 16) = v;
      } else {
        int h = ((n0 + wc * 64) >> 5) + (cch >> 2);
        *(uint4*)((char*)(Y + ((size_t)(((n & 63) << 3) | h) * S_ + (n >> 6)) *
                                  DK_) +
                  (cch & 3) * 16) = v;
      }
    }
  }
}

// fused QKV: grid (224, 6); y>>1 selects matrix, y&1 selects col-half
__global__ __launch_bounds__(256, 2) void gemm_qkv_kernel(
    const bf16_t* __restrict__ A, const bf16_t* __restrict__ wq,
    const bf16_t* __restrict__ wk, const bf16_t* __restrict__ wvp,
    const float* __restrict__ bq, const float* __restrict__ bk,
    const float* __restrict__ bvp, bf16_t* __restrict__ yq,
    bf16_t* __restrict__ yk, bf16_t* __restrict__ yv) {
  int sel = blockIdx.y >> 1;
  const bf16_t* W = sel == 0 ? wq : sel == 1 ? wk : wvp;
  const float* bb = sel == 0 ? bq : sel == 1 ? bk : bvp;
  bf16_t* Y = sel == 0 ? yq : sel == 1 ? yk : yv;
  gemm_body<0, 1, 0>(A, W, bb, Y, blockIdx.x * 128, (blockIdx.y & 1) * 128);
}

__global__ __launch_bounds__(256, 2) void gemm_ctx_kernel(
    const bf16_t* __restrict__ A, const bf16_t* __restrict__ Wt,
    const float* __restrict__ bias, bf16_t* __restrict__ Y) {
  gemm_body<1, 0, 0>(A, Wt, bias, Y, blockIdx.x * 128, blockIdx.y * 128);
}
__global__ __launch_bounds__(256, 2) void gemm_relu_kernel(
    const bf16_t* __restrict__ A, const bf16_t* __restrict__ Wt,
    const float* __restrict__ bias, bf16_t* __restrict__ Y) {
  gemm_body<0, 0, 1>(A, Wt, bias, Y, blockIdx.x * 128, blockIdx.y * 128);
}
__global__ __launch_bounds__(256, 2) void gemm_plain_kernel(
    const bf16_t* __restrict__ A, const bf16_t* __restrict__ Wt,
    const float* __restrict__ bias, bf16_t* __restrict__ Y) {
  gemm_body<0, 0, 0>(A, Wt, bias, Y, blockIdx.x * 128, blockIdx.y * 128);
}

// ---------------------------------------------------------------- attention
// one block per (b,h) panel; 4 waves, each owns 16-q tiles, 7 iterations.
__global__ __launch_bounds__(256, 2) void attn_mfma_kernel(
    bf16_t* __restrict__ Q, const bf16_t* __restrict__ K,
    const bf16_t* __restrict__ V) {
  __shared__ bf16_t Ks[448][32];     // [t][dk], slot-swizzled (28672 B)
  __shared__ bf16_t Vt[32][448];     // [dk][t], XOR-swizzled   (28672 B)
  __shared__ bf16_t Pb[4][16][32];   // per-wave P chunk / ctx  (4096 B)
  int tid = threadIdx.x, lane = tid & 63, wv = tid >> 6;
  int bh = blockIdx.x;
  bf16_t* Qp = Q + (size_t)bh * PANEL_;
  const bf16_t* Kp = K + (size_t)bh * PANEL_;
  const bf16_t* Vp = V + (size_t)bh * PANEL_;
  int jg = lane >> 4, fr = lane & 15;

  // ---- stage K: rows wv*112 + i*16 + (lane>>2), slot p = lane&3
#pragma unroll
  for (int i = 0; i < 7; ++i) {
    int row = wv * 112 + i * 16 + (lane >> 2);
    int p = lane & 3;
    int ls = p ^ ((row >> 1) & 3);
    *(uint4*)(&Ks[row][p * 8]) = *(const uint4*)(Kp + row * 32 + ls * 8);
  }
  // ---- stage V transposed: Vt[dk][t], byte ^= ((dk&7)<<4)
  for (int idx = tid; idx < 448 * 4; idx += 256) {
    int t = idx >> 2, c = idx & 3;
    uint4 vv = *(const uint4*)(Vp + t * 32 + c * 8);
    unsigned w[4] = {vv.x, vv.y, vv.z, vv.w};
#pragma unroll
    for (int e = 0; e < 8; ++e) {
      int dk = c * 8 + e;
      bf16_t val = (bf16_t)((e & 1) ? (w[e >> 1] >> 16) : (w[e >> 1] & 0xffff));
      int byteoff = (((dk * 448 + t) << 1)) ^ ((dk & 7) << 4);
      *(bf16_t*)((char*)&Vt[0][0] + byteoff) = val;
    }
  }
  __syncthreads();

  const float sc_c = 0.25503484f;    // log2(e)/sqrt(32)
  f32x4 zero = {0.f, 0.f, 0.f, 0.f};
  char* pbase = (char*)&Pb[0][0][0] + wv * 1024;

  for (int qt = 0; qt < 7; ++qt) {
    int q0 = qt * 64 + wv * 16;
    // Q A-fragment straight from global: lane holds Q[q0+fr][jg*8..+7]
    bf16x8 qf = *(const bf16x8*)(Qp + (q0 + fr) * 32 + jg * 8);

    // ---- QK^T: 28 tiles of 16 t
    f32x4 s[28];
#pragma unroll
    for (int ct = 0; ct < 28; ++ct) {
      int trow = ct * 16 + fr;
      bf16x8 kf = *(const bf16x8*)((const char*)&Ks[0][0] + trow * 64 +
                                   ((jg ^ ((trow >> 1) & 3)) << 4));
      s[ct] = __builtin_amdgcn_mfma_f32_16x16x32_bf16(qf, kf, zero, 0, 0, 0);
    }
    // lane holds S[q = jg*4+r][t = ct*16+fr]
    // ---- softmax (max over t; exp2; sum; normalization deferred to O)
    float inv[4];
#pragma unroll
    for (int r = 0; r < 4; ++r) {
      float m = s[0][r];
#pragma unroll
      for (int ct = 1; ct < 28; ++ct) m = fmaxf(m, s[ct][r]);
      m = fmaxf(m, __shfl_xor(m, 1));
      m = fmaxf(m, __shfl_xor(m, 2));
      m = fmaxf(m, __shfl_xor(m, 4));
      m = fmaxf(m, __shfl_xor(m, 8));
      float l = 0.f;
#pragma unroll
      for (int ct = 0; ct < 28; ++ct) {
        float p = exp2f((s[ct][r] - m) * sc_c);
        s[ct][r] = p;
        l += p;
      }
      l += __shfl_xor(l, 1);
      l += __shfl_xor(l, 2);
      l += __shfl_xor(l, 4);
      l += __shfl_xor(l, 8);
      inv[r] = 1.f / l;
    }
    // ---- PV: 14 chunks of 32 t
    f32x4 o[2] = {zero, zero};
#pragma unroll
    for (int c = 0; c < 14; ++c) {
      // write P chunk (bf16) into per-wave LDS, slot-swizzled rows of 64B
#pragma unroll
      for (int half = 0; half < 2; ++half)
#pragma unroll
        for (int r = 0; r < 4; ++r) {
          int q = jg * 4 + r;
          int tl = fr + 16 * half;
          int byteoff = q * 64 + ((tl ^ (((q >> 1) & 3) << 3)) << 1);
          *(bf16_t*)(pbase + byteoff) = f2b(s[2 * c + half][r]);
        }
      bf16x8 pf = *(const bf16x8*)(pbase + fr * 64 +
                                   ((jg ^ ((fr >> 1) & 3)) << 4));
#pragma unroll
      for (int nt = 0; nt < 2; ++nt) {
        int dk = nt * 16 + fr;
        int byt = (((dk * 448 + c * 32 + jg * 8) << 1)) ^ ((dk & 7) << 4);
        bf16x8 vf = *(const bf16x8*)((const char*)&Vt[0][0] + byt);
        o[nt] = __builtin_amdgcn_mfma_f32_16x16x32_bf16(pf, vf, o[nt], 0, 0, 0);
      }
    }
    // ---- scale by 1/l, transpose via per-wave LDS, 16B/lane store
#pragma unroll
    for (int nt = 0; nt < 2; ++nt)
#pragma unroll
      for (int r = 0; r < 4; ++r) {
        float v = o[nt][r] * inv[r];
        int row = jg * 4 + r;
        int cb = (nt * 16 + fr) * 2;
        *(bf16_t*)(pbase + row * 64 + (cb ^ (jg << 4))) = f2b(v);
      }
    {
      int row16 = lane >> 2, c = lane & 3;
      uint4 v = *(uint4*)(pbase + row16 * 64 +
                          ((c << 4) ^ (((row16 >> 2) & 3) << 4)));
      *(uint4*)(Qp + (q0 + row16) * 32 + c * 8) = v;
    }
  }
}

// ---------------------------------------------------------------- residual+LN
// 1 token per wave, 4 tokens per block, ushort4-vectorized, no LDS.
__global__ __launch_bounds__(256) void resid_ln_kernel(
    bf16_t* __restrict__ x, const bf16_t* __restrict__ y,
    const float* __restrict__ g, const float* __restrict__ be) {
  int wv = threadIdx.x >> 6, lane = threadIdx.x & 63;
  size_t n = (size_t)blockIdx.x * 4 + wv;
  size_t off = n * D_ + lane * 4;
  ushort4 xv = *(const ushort4*)(x + off);
  ushort4 yv = *(const ushort4*)(y + off);
  float v[4];
  v[0] = b2f(xv.x) + b2f(yv.x);
  v[1] = b2f(xv.y) + b2f(yv.y);
  v[2] = b2f(xv.z) + b2f(yv.z);
  v[3] = b2f(xv.w) + b2f(yv.w);
  float sm = v[0] + v[1] + v[2] + v[3];
#pragma unroll
  for (int o = 32; o; o >>= 1) sm += __shfl_xor(sm, o);
  float mean = sm * (1.f / 256.f);
  float c[4], s2 = 0.f;
#pragma unroll
  for (int i = 0; i < 4; ++i) { c[i] = v[i] - mean; s2 += c[i] * c[i]; }
#pragma unroll
  for (int o = 32; o; o >>= 1) s2 += __shfl_xor(s2, o);
  float var = s2 * (1.f / 256.f);
  float r = rsqrtf(var + 1e-5f);
  float4 gv = *(const float4*)(g + lane * 4);
  float4 bv = *(const float4*)(be + lane * 4);
  ushort4 ov;
  ov.x = f2b(c[0] * r * gv.x + bv.x);
  ov.y = f2b(c[1] * r * gv.y + bv.y);
  ov.z = f2b(c[2] * r * gv.z + bv.z);
  ov.w = f2b(c[3] * r * gv.w + bv.w);
  *(ushort4*)(x + off) = ov;
}

// ---------------------------------------------------------------- out proj
__global__ __launch_bounds__(256) void out_kernel(
    const bf16_t* __restrict__ x, const float* __restrict__ w_out,
    const float* __restrict__ b_out, float* __restrict__ out) {
  int idx = blockIdx.x * 256 + threadIdx.x;  // (p*B+b)*F + f
  int f = idx & 7;
  int pb = idx >> 3;
  const bf16_t* xrow = x + ((size_t)(S_ - PRED_) * B_ + pb) * D_;
  float acc = b_out[f];
  for (int dd = 0; dd < D_; ++dd) acc += b2f(xrow[dd]) * w_out[dd * F_ + f];
  out[idx] = acc;
}

// ---------------------------------------------------------------- launch
extern "C" void kernel_launch(void* const* d_in, const int* in_sizes, int n_in,
                              void* d_out, int out_size, void* d_ws, size_t ws_size,
                              hipStream_t stream) {
  const float* src  = (const float*)d_in[0];
  const float* w_in = (const float*)d_in[1];
  const float* b_in = (const float*)d_in[2];
  const float* Wq = (const float*)d_in[3];
  const float* bq = (const float*)d_in[4];
  const float* Wk = (const float*)d_in[5];
  const float* bk = (const float*)d_in[6];
  const float* Wv = (const float*)d_in[7];
  const float* bv = (const float*)d_in[8];
  const float* Wo = (const float*)d_in[9];
  const float* bo = (const float*)d_in[10];
  const float* g1 = (const float*)d_in[11];
  const float* be1 = (const float*)d_in[12];
  const float* W1 = (const float*)d_in[13];
  const float* b1 = (const float*)d_in[14];
  const float* W2 = (const float*)d_in[15];
  const float* b2 = (const float*)d_in[16];
  const float* g2 = (const float*)d_in[17];
  const float* be2 = (const float*)d_in[18];
  const float* w_out = (const float*)d_in[19];
  const float* b_out = (const float*)d_in[20];
  float* out = (float*)d_out;

  const size_t NTD = (size_t)NT_ * D_;
  bf16_t* xb = (bf16_t*)d_ws;        // token-major [n][256]
  bf16_t* qb = xb + NTD;             // panel [(b,h)][448][32] (or tok-major)
  bf16_t* kb = qb + NTD;
  bf16_t* vb = kb + NTD;
  bf16_t* wt = vb + NTD;             // 6 * L * 65536 bf16 = 3.1 MB
  const size_t WSZ = (size_t)L_ * 65536;
  bf16_t* wtq = wt;
  bf16_t* wtk = wtq + WSZ;
  bf16_t* wtv = wtk + WSZ;
  bf16_t* wto = wtv + WSZ;
  bf16_t* wt1 = wto + WSZ;
  bf16_t* wt2 = wt1 + WSZ;

  dim3 tb(32, 8), tg(8, 8, L_);
  transpose_w_kernel<<<tg, tb, 0, stream>>>(Wq, wtq);
  transpose_w_kernel<<<tg, tb, 0, stream>>>(Wk, wtk);
  transpose_w_kernel<<<tg, tb, 0, stream>>>(Wv, wtv);
  transpose_w_kernel<<<tg, tb, 0, stream>>>(Wo, wto);
  transpose_w_kernel<<<tg, tb, 0, stream>>>(W1, wt1);
  transpose_w_kernel<<<tg, tb, 0, stream>>>(W2, wt2);

  embed_kernel<<<NT_, 256, 0, stream>>>(src, w_in, b_in, xb);

  dim3 gg(224, 2);
  for (int l = 0; l < L_; ++l) {
    const size_t woff = (size_t)l * 65536;
    const size_t boff = (size_t)l * D_;
    gemm_qkv_kernel<<<dim3(224, 6), 256, 0, stream>>>(
        xb, wtq + woff, wtk + woff, wtv + woff, bq + boff, bk + boff,
        bv + boff, qb, kb, vb);
    attn_mfma_kernel<<<512, 256, 0, stream>>>(qb, kb, vb);
    gemm_ctx_kernel<<<gg, 256, 0, stream>>>(qb, wto + woff, bo + boff, kb);
    resid_ln_kernel<<<NT_ / 4, 256, 0, stream>>>(xb, kb, g1 + boff, be1 + boff);
    gemm_relu_kernel<<<gg, 256, 0, stream>>>(xb, wt1 + woff, b1 + boff, qb);
    gemm_plain_kernel<<<gg, 256, 0, stream>>>(qb, wt2 + woff, b2 + boff, kb);
    resid_ln_kernel<<<NT_ / 4, 256, 0, stream>>>(xb, kb, g2 + boff, be2 + boff);
  }

  out_kernel<<<(PRED_ * B_ * F_) / 256, 256, 0, stream>>>(xb, w_out, b_out, out);
}

// Round 7
// 631.514 us; speedup vs baseline: 1.1601x; 1.1601x over previous
//
#include <hip/hip_runtime.h>
#include <math.h>

#define S_ 448
#define B_ 64
#define F_ 8
#define D_ 256
#define H_ 8
#define DK_ 32
#define L_ 4
#define PRED_ 96
#define NT_ (S_ * B_)          // 28672 tokens
#define PANEL_ (S_ * DK_)      // 14336 elems per (b,h) panel

typedef unsigned short bf16_t;
using bf16x8 = __attribute__((ext_vector_type(8))) short;   // 8 bf16 = 4 VGPR
using f32x4  = __attribute__((ext_vector_type(4))) float;   // MFMA acc

__device__ __forceinline__ float b2f(bf16_t b) {
  return __uint_as_float(((unsigned)b) << 16);
}
__device__ __forceinline__ bf16_t f2b(float f) {
  unsigned u = __float_as_uint(f);
  u += 0x7fffu + ((u >> 16) & 1u);     // round-to-nearest-even
  return (bf16_t)(u >> 16);
}

// ---------------------------------------------------------------- embed
__global__ __launch_bounds__(256) void embed_kernel(
    const float* __restrict__ src, const float* __restrict__ w_in,
    const float* __restrict__ b_in, bf16_t* __restrict__ x) {
  int n = blockIdx.x;          // token = s*B + b
  int d = threadIdx.x;         // 0..255
  const float* srow = src + (size_t)n * F_;
  float acc = b_in[d];
#pragma unroll
  for (int f = 0; f < F_; ++f) acc += srow[f] * w_in[f * D_ + d];
  int s = n / B_;
  int i2 = d & ~1;             // 2*i
  float freq = __expf(-9.210340371976184f * (float)i2 / (float)D_);
  float ang = (float)s * freq;
  float pe = (d & 1) ? cosf(ang) : sinf(ang);
  x[(size_t)n * D_ + d] = f2b(acc + pe);
}

// ------------------------------------------- weight transpose+convert prep
// Wt[l][n][k] (bf16) = W[l][k][n] (f32);  grid (8,8,L), block (32,8)
__global__ __launch_bounds__(256) void transpose_w_kernel(
    const float* __restrict__ W, bf16_t* __restrict__ Wt) {
  __shared__ float t[32][33];
  int l = blockIdx.z;
  int k0 = blockIdx.x * 32, n0 = blockIdx.y * 32;
  int x = threadIdx.x, y = threadIdx.y;
  const float* src = W + ((size_t)l * 256 + k0) * 256 + n0;
#pragma unroll
  for (int i = y; i < 32; i += 8) t[i][x] = src[(size_t)i * 256 + x];
  __syncthreads();
  bf16_t* dst = Wt + ((size_t)l * 256 + n0) * 256 + k0;
#pragma unroll
  for (int i = y; i < 32; i += 8) dst[(size_t)i * 256 + x] = f2b(t[x][i]);
}

// ------------------------------------------------- MFMA GEMM 128x128, BK=32
// 512 threads, 8 waves in a 2x4 grid (wave tile 64 rows x 32 cols).
// ALAY: 0 = token-major [n][256], 1 = head-panel [(b*8+h)][s][dk]
template <int ALAY, int OLAY, int RELU>
__device__ __forceinline__ void gemm_body(
    const bf16_t* __restrict__ A, const bf16_t* __restrict__ Wt,
    const float* __restrict__ bias, bf16_t* __restrict__ Y, int m0, int n0) {
  __shared__ bf16_t As[2][128][32];
  __shared__ bf16_t Bs[2][128][32];
  int tid = threadIdx.x, lane = tid & 63, wv = tid >> 6;
  int wr = wv >> 2, wc = wv & 3;           // wave 64x32 sub-tile
  int jg = lane >> 4, fr = lane & 15;
  int s_row = tid >> 2;                    // 0..127, one row per thread
  int s_p = tid & 3;

  uint4 rA, rB;

  auto stage_load = [&](int kt) {
    int k0 = kt * 32;
    int ls = s_p ^ ((s_row >> 1) & 3);
    const bf16_t* ap;
    if (ALAY == 0) {
      ap = A + (size_t)(m0 + s_row) * 256 + k0 + ls * 8;
    } else {
      int n = m0 + s_row;                  // token: s = n>>6, b = n&63
      int k = k0 + ls * 8;                 // d: h = k>>5, dk = k&31
      ap = A + ((size_t)(((n & 63) << 3) | (k >> 5)) * S_ + (n >> 6)) * DK_ +
           (k & 31);
    }
    rA = *(const uint4*)ap;
    rB = *(const uint4*)(Wt + (size_t)(n0 + s_row) * 256 + k0 + ls * 8);
  };
  auto stage_write = [&](int buf) {
    *(uint4*)(&As[buf][s_row][s_p * 8]) = rA;
    *(uint4*)(&Bs[buf][s_row][s_p * 8]) = rB;
  };

  f32x4 zero = {0.f, 0.f, 0.f, 0.f};
  f32x4 acc[4][2];
#pragma unroll
  for (int i = 0; i < 4; ++i)
#pragma unroll
    for (int j = 0; j < 2; ++j) acc[i][j] = zero;

  stage_load(0);
  stage_write(0);
  __syncthreads();

  for (int kt = 0; kt < 8; ++kt) {
    int buf = kt & 1;
    if (kt < 7) stage_load(kt + 1);
    bf16x8 af[4], bfr[2];
#pragma unroll
    for (int mi = 0; mi < 4; ++mi) {
      int row = wr * 64 + mi * 16 + fr;
      af[mi] = *(const bf16x8*)((const char*)&As[buf][0][0] + row * 64 +
                                ((jg ^ ((row >> 1) & 3)) << 4));
    }
#pragma unroll
    for (int ni = 0; ni < 2; ++ni) {
      int rn = wc * 32 + ni * 16 + fr;
      bfr[ni] = *(const bf16x8*)((const char*)&Bs[buf][0][0] + rn * 64 +
                                 ((jg ^ ((rn >> 1) & 3)) << 4));
    }
#pragma unroll
    for (int mi = 0; mi < 4; ++mi)
#pragma unroll
      for (int ni = 0; ni < 2; ++ni)
        acc[mi][ni] = __builtin_amdgcn_mfma_f32_16x16x32_bf16(
            af[mi], bfr[ni], acc[mi][ni], 0, 0, 0);
    if (kt < 7) {
      stage_write((kt + 1) & 1);
      __syncthreads();
    }
  }

  // ---- epilogue: per-wave LDS transpose -> 16B/lane coalesced stores
  __syncthreads();            // everyone done reading As/Bs
  char* ep0 = (char*)&As[0][0][0] + wv * 1024;   // 16 rows x 64 B per wave
  float bcol[2];
#pragma unroll
  for (int ni = 0; ni < 2; ++ni) bcol[ni] = bias[n0 + wc * 32 + ni * 16 + fr];
#pragma unroll
  for (int mi = 0; mi < 4; ++mi) {
    char* ep = ep0 + (mi & 1) * 8192;            // WAR double-buffer
#pragma unroll
    for (int ni = 0; ni < 2; ++ni)
#pragma unroll
      for (int r = 0; r < 4; ++r) {
        float v = acc[mi][ni][r] + bcol[ni];
        if (RELU) v = fmaxf(v, 0.f);
        int row = jg * 4 + r;
        int cb = (ni * 16 + fr) * 2;
        *(bf16_t*)(ep + row * 64 + (cb ^ (jg << 4))) = f2b(v);
      }
    int row16 = lane >> 2, c = lane & 3;
    uint4 v = *(uint4*)(ep + row16 * 64 +
                        ((c << 4) ^ (((row16 >> 2) & 3) << 4)));
    int n = m0 + wr * 64 + mi * 16 + row16;
    if (OLAY == 0) {
      *(uint4*)((char*)(Y + (size_t)n * 256 + n0 + wc * 32) + c * 16) = v;
    } else {
      int h = (n0 + wc * 32) >> 5;               // one head per wave
      *(uint4*)((char*)(Y + ((size_t)(((n & 63) << 3) | h) * S_ + (n >> 6)) *
                                DK_) +
                c * 16) = v;
    }
  }
}

// fused QKV: grid (224, 6); y>>1 selects matrix, y&1 selects col-half
__global__ __launch_bounds__(512, 4) void gemm_qkv_kernel(
    const bf16_t* __restrict__ A, const bf16_t* __restrict__ wq,
    const bf16_t* __restrict__ wk, const bf16_t* __restrict__ wvp,
    const float* __restrict__ bq, const float* __restrict__ bk,
    const float* __restrict__ bvp, bf16_t* __restrict__ yq,
    bf16_t* __restrict__ yk, bf16_t* __restrict__ yv) {
  int sel = blockIdx.y >> 1;
  const bf16_t* W = sel == 0 ? wq : sel == 1 ? wk : wvp;
  const float* bb = sel == 0 ? bq : sel == 1 ? bk : bvp;
  bf16_t* Y = sel == 0 ? yq : sel == 1 ? yk : yv;
  gemm_body<0, 1, 0>(A, W, bb, Y, blockIdx.x * 128, (blockIdx.y & 1) * 128);
}

__global__ __launch_bounds__(512, 4) void gemm_ctx_kernel(
    const bf16_t* __restrict__ A, const bf16_t* __restrict__ Wt,
    const float* __restrict__ bias, bf16_t* __restrict__ Y) {
  gemm_body<1, 0, 0>(A, Wt, bias, Y, blockIdx.x * 128, blockIdx.y * 128);
}
__global__ __launch_bounds__(512, 4) void gemm_relu_kernel(
    const bf16_t* __restrict__ A, const bf16_t* __restrict__ Wt,
    const float* __restrict__ bias, bf16_t* __restrict__ Y) {
  gemm_body<0, 0, 1>(A, Wt, bias, Y, blockIdx.x * 128, blockIdx.y * 128);
}
__global__ __launch_bounds__(512, 4) void gemm_plain_kernel(
    const bf16_t* __restrict__ A, const bf16_t* __restrict__ Wt,
    const float* __restrict__ bias, bf16_t* __restrict__ Y) {
  gemm_body<0, 0, 0>(A, Wt, bias, Y, blockIdx.x * 128, blockIdx.y * 128);
}

// ---------------------------------------------------------------- attention
// grid (512, 4): x = (b,h) panel, y = 128-q chunk; 8 waves, 1 q-tile each.
__global__ __launch_bounds__(512, 4) void attn_mfma_kernel(
    bf16_t* __restrict__ Q, const bf16_t* __restrict__ K,
    const bf16_t* __restrict__ V) {
  __shared__ bf16_t Ks[448][32];     // [t][dk], slot-swizzled (28672 B)
  __shared__ bf16_t Vt[32][448];     // [dk][t], XOR-swizzled  (28672 B)
  __shared__ bf16_t Pb[8][16][32];   // per-wave P chunk / ctx (8192 B)
  int tid = threadIdx.x, lane = tid & 63, wv = tid >> 6;
  int bh = blockIdx.x;
  bf16_t* Qp = Q + (size_t)bh * PANEL_;
  const bf16_t* Kp = K + (size_t)bh * PANEL_;
  const bf16_t* Vp = V + (size_t)bh * PANEL_;
  int jg = lane >> 4, fr = lane & 15;

  // ---- stage K: slot-swizzled rows
  for (int idx = tid; idx < 448 * 4; idx += 512) {
    int row = idx >> 2, p = idx & 3;
    int ls = p ^ ((row >> 1) & 3);
    *(uint4*)(&Ks[row][p * 8]) = *(const uint4*)(Kp + row * 32 + ls * 8);
  }
  // ---- stage V transposed: Vt[dk][t], byte ^= ((dk&7)<<4)
  for (int idx = tid; idx < 448 * 4; idx += 512) {
    int t = idx >> 2, c = idx & 3;
    uint4 vv = *(const uint4*)(Vp + t * 32 + c * 8);
    unsigned w[4] = {vv.x, vv.y, vv.z, vv.w};
#pragma unroll
    for (int e = 0; e < 8; ++e) {
      int dk = c * 8 + e;
      bf16_t val = (bf16_t)((e & 1) ? (w[e >> 1] >> 16) : (w[e >> 1] & 0xffff));
      int byteoff = (((dk * 448 + t) << 1)) ^ ((dk & 7) << 4);
      *(bf16_t*)((char*)&Vt[0][0] + byteoff) = val;
    }
  }
  __syncthreads();

  int q0 = blockIdx.y * 128 + wv * 16;
  if (q0 < S_) {
    const float sc_c = 0.25503484f;    // log2(e)/sqrt(32)
    f32x4 zero = {0.f, 0.f, 0.f, 0.f};
    char* pbase = (char*)&Pb[0][0][0] + wv * 1024;

    // Q A-fragment straight from global: lane holds Q[q0+fr][jg*8..+7]
    bf16x8 qf = *(const bf16x8*)(Qp + (q0 + fr) * 32 + jg * 8);

    // ---- QK^T: 28 tiles of 16 t
    f32x4 s[28];
#pragma unroll
    for (int ct = 0; ct < 28; ++ct) {
      int trow = ct * 16 + fr;
      bf16x8 kf = *(const bf16x8*)((const char*)&Ks[0][0] + trow * 64 +
                                   ((jg ^ ((trow >> 1) & 3)) << 4));
      s[ct] = __builtin_amdgcn_mfma_f32_16x16x32_bf16(qf, kf, zero, 0, 0, 0);
    }
    // lane holds S[q = jg*4+r][t = ct*16+fr]
    // ---- softmax (max over t; exp2; sum; normalization deferred to O)
    float inv[4];
#pragma unroll
    for (int r = 0; r < 4; ++r) {
      float m = s[0][r];
#pragma unroll
      for (int ct = 1; ct < 28; ++ct) m = fmaxf(m, s[ct][r]);
      m = fmaxf(m, __shfl_xor(m, 1));
      m = fmaxf(m, __shfl_xor(m, 2));
      m = fmaxf(m, __shfl_xor(m, 4));
      m = fmaxf(m, __shfl_xor(m, 8));
      float l = 0.f;
#pragma unroll
      for (int ct = 0; ct < 28; ++ct) {
        float p = exp2f((s[ct][r] - m) * sc_c);
        s[ct][r] = p;
        l += p;
      }
      l += __shfl_xor(l, 1);
      l += __shfl_xor(l, 2);
      l += __shfl_xor(l, 4);
      l += __shfl_xor(l, 8);
      inv[r] = 1.f / l;
    }
    // ---- PV: 14 chunks of 32 t
    f32x4 o[2] = {zero, zero};
#pragma unroll
    for (int c = 0; c < 14; ++c) {
      // write P chunk (bf16) into per-wave LDS, slot-swizzled rows of 64B
#pragma unroll
      for (int half = 0; half < 2; ++half)
#pragma unroll
        for (int r = 0; r < 4; ++r) {
          int q = jg * 4 + r;
          int tl = fr + 16 * half;
          int byteoff = q * 64 + ((tl ^ (((q >> 1) & 3) << 3)) << 1);
          *(bf16_t*)(pbase + byteoff) = f2b(s[2 * c + half][r]);
        }
      bf16x8 pf = *(const bf16x8*)(pbase + fr * 64 +
                                   ((jg ^ ((fr >> 1) & 3)) << 4));
#pragma unroll
      for (int nt = 0; nt < 2; ++nt) {
        int dk = nt * 16 + fr;
        int byt = (((dk * 448 + c * 32 + jg * 8) << 1)) ^ ((dk & 7) << 4);
        bf16x8 vf = *(const bf16x8*)((const char*)&Vt[0][0] + byt);
        o[nt] = __builtin_amdgcn_mfma_f32_16x16x32_bf16(pf, vf, o[nt], 0, 0, 0);
      }
    }
    // ---- scale by 1/l, transpose via per-wave LDS, 16B/lane store
#pragma unroll
    for (int nt = 0; nt < 2; ++nt)
#pragma unroll
      for (int r = 0; r < 4; ++r) {
        float v = o[nt][r] * inv[r];
        int row = jg * 4 + r;
        int cb = (nt * 16 + fr) * 2;
        *(bf16_t*)(pbase + row * 64 + (cb ^ (jg << 4))) = f2b(v);
      }
    {
      int row16 = lane >> 2, c = lane & 3;
      uint4 v = *(uint4*)(pbase + row16 * 64 +
                          ((c << 4) ^ (((row16 >> 2) & 3) << 4)));
      *(uint4*)(Qp + (q0 + row16) * 32 + c * 8) = v;
    }
  }
}

// ---------------------------------------------------------------- residual+LN
// 1 token per wave, 4 tokens per block, ushort4-vectorized, no LDS.
__global__ __launch_bounds__(256) void resid_ln_kernel(
    bf16_t* __restrict__ x, const bf16_t* __restrict__ y,
    const float* __restrict__ g, const float* __restrict__ be) {
  int wv = threadIdx.x >> 6, lane = threadIdx.x & 63;
  size_t n = (size_t)blockIdx.x * 4 + wv;
  size_t off = n * D_ + lane * 4;
  ushort4 xv = *(const ushort4*)(x + off);
  ushort4 yv = *(const ushort4*)(y + off);
  float v[4];
  v[0] = b2f(xv.x) + b2f(yv.x);
  v[1] = b2f(xv.y) + b2f(yv.y);
  v[2] = b2f(xv.z) + b2f(yv.z);
  v[3] = b2f(xv.w) + b2f(yv.w);
  float sm = v[0] + v[1] + v[2] + v[3];
#pragma unroll
  for (int o = 32; o; o >>= 1) sm += __shfl_xor(sm, o);
  float mean = sm * (1.f / 256.f);
  float c[4], s2 = 0.f;
#pragma unroll
  for (int i = 0; i < 4; ++i) { c[i] = v[i] - mean; s2 += c[i] * c[i]; }
#pragma unroll
  for (int o = 32; o; o >>= 1) s2 += __shfl_xor(s2, o);
  float var = s2 * (1.f / 256.f);
  float r = rsqrtf(var + 1e-5f);
  float4 gv = *(const float4*)(g + lane * 4);
  float4 bv = *(const float4*)(be + lane * 4);
  ushort4 ov;
  ov.x = f2b(c[0] * r * gv.x + bv.x);
  ov.y = f2b(c[1] * r * gv.y + bv.y);
  ov.z = f2b(c[2] * r * gv.z + bv.z);
  ov.w = f2b(c[3] * r * gv.w + bv.w);
  *(ushort4*)(x + off) = ov;
}

// ---------------------------------------------------------------- out proj
__global__ __launch_bounds__(256) void out_kernel(
    const bf16_t* __restrict__ x, const float* __restrict__ w_out,
    const float* __restrict__ b_out, float* __restrict__ out) {
  int idx = blockIdx.x * 256 + threadIdx.x;  // (p*B+b)*F + f
  int f = idx & 7;
  int pb = idx >> 3;
  const bf16_t* xrow = x + ((size_t)(S_ - PRED_) * B_ + pb) * D_;
  float acc = b_out[f];
  for (int dd = 0; dd < D_; ++dd) acc += b2f(xrow[dd]) * w_out[dd * F_ + f];
  out[idx] = acc;
}

// ---------------------------------------------------------------- launch
extern "C" void kernel_launch(void* const* d_in, const int* in_sizes, int n_in,
                              void* d_out, int out_size, void* d_ws, size_t ws_size,
                              hipStream_t stream) {
  const float* src  = (const float*)d_in[0];
  const float* w_in = (const float*)d_in[1];
  const float* b_in = (const float*)d_in[2];
  const float* Wq = (const float*)d_in[3];
  const float* bq = (const float*)d_in[4];
  const float* Wk = (const float*)d_in[5];
  const float* bk = (const float*)d_in[6];
  const float* Wv = (const float*)d_in[7];
  const float* bv = (const float*)d_in[8];
  const float* Wo = (const float*)d_in[9];
  const float* bo = (const float*)d_in[10];
  const float* g1 = (const float*)d_in[11];
  const float* be1 = (const float*)d_in[12];
  const float* W1 = (const float*)d_in[13];
  const float* b1 = (const float*)d_in[14];
  const float* W2 = (const float*)d_in[15];
  const float* b2 = (const float*)d_in[16];
  const float* g2 = (const float*)d_in[17];
  const float* be2 = (const float*)d_in[18];
  const float* w_out = (const float*)d_in[19];
  const float* b_out = (const float*)d_in[20];
  float* out = (float*)d_out;

  const size_t NTD = (size_t)NT_ * D_;
  bf16_t* xb = (bf16_t*)d_ws;        // token-major [n][256]
  bf16_t* qb = xb + NTD;             // panel [(b,h)][448][32] (or tok-major)
  bf16_t* kb = qb + NTD;
  bf16_t* vb = kb + NTD;
  bf16_t* wt = vb + NTD;             // 6 * L * 65536 bf16 = 3.1 MB
  const size_t WSZ = (size_t)L_ * 65536;
  bf16_t* wtq = wt;
  bf16_t* wtk = wtq + WSZ;
  bf16_t* wtv = wtk + WSZ;
  bf16_t* wto = wtv + WSZ;
  bf16_t* wt1 = wto + WSZ;
  bf16_t* wt2 = wt1 + WSZ;

  dim3 tb(32, 8), tg(8, 8, L_);
  transpose_w_kernel<<<tg, tb, 0, stream>>>(Wq, wtq);
  transpose_w_kernel<<<tg, tb, 0, stream>>>(Wk, wtk);
  transpose_w_kernel<<<tg, tb, 0, stream>>>(Wv, wtv);
  transpose_w_kernel<<<tg, tb, 0, stream>>>(Wo, wto);
  transpose_w_kernel<<<tg, tb, 0, stream>>>(W1, wt1);
  transpose_w_kernel<<<tg, tb, 0, stream>>>(W2, wt2);

  embed_kernel<<<NT_, 256, 0, stream>>>(src, w_in, b_in, xb);

  dim3 gg(224, 2);
  for (int l = 0; l < L_; ++l) {
    const size_t woff = (size_t)l * 65536;
    const size_t boff = (size_t)l * D_;
    gemm_qkv_kernel<<<dim3(224, 6), 512, 0, stream>>>(
        xb, wtq + woff, wtk + woff, wtv + woff, bq + boff, bk + boff,
        bv + boff, qb, kb, vb);
    attn_mfma_kernel<<<dim3(512, 4), 512, 0, stream>>>(qb, kb, vb);
    gemm_ctx_kernel<<<gg, 512, 0, stream>>>(qb, wto + woff, bo + boff, kb);
    resid_ln_kernel<<<NT_ / 4, 256, 0, stream>>>(xb, kb, g1 + boff, be1 + boff);
    gemm_relu_kernel<<<gg, 512, 0, stream>>>(xb, wt1 + woff, b1 + boff, qb);
    gemm_plain_kernel<<<gg, 512, 0, stream>>>(qb, wt2 + woff, b2 + boff, kb);
    resid_ln_kernel<<<NT_ / 4, 256, 0, stream>>>(xb, kb, g2 + boff, be2 + boff);
  }

  out_kernel<<<(PRED_ * B_ * F_) / 256, 256, 0, stream>>>(xb, w_out, b_out, out);
}